// Round 5
// baseline (153.685 us; speedup 1.0000x reference)
//
#include <hip/hip_runtime.h>

// SSIM loss over [8,8,3,256,256] fp32.
// Wave-per-band structure, packed-FP16 convolutions (v_pk_fma_f16). Epilogue
// (variance differencing + rcp) stays fp32.
// R10: BAND 16->8 + 4 waves/block. Occupancy 26->40, band 78->73us.
// R11: BAND 8->4 + hoisted bpermute. Neutral.
// R12: launch_bounds(256,4) alone. Neutral; VGPR stuck at 52.
// ERRATA (R13): FETCH/WRITE are KB not MB; HBM was always clean. The real
//   spill was rule-#20: runtime-indexed ring in a rolled loop -> scratch,
//   regardless of launch bounds.
// R13: full 4x unroll (ring -> SSA) + sum/diff channels (5->4 convs).
//   band 67->60.6us, VGPR 52->44, Occupancy 43. VALUBusy still ~60%:
//   remaining stall = 24 ds_bpermute/row on the DS pipe (lgkmcnt waits).
// R14: horizontal shifts via DPP wave_shr:1/wave_shl:1 (v_mov_b32_dpp,
//   VALU pipe, zero DS). bound_ctrl zero-fill at wave edges == image-edge
//   zero-pad (wave spans the full 256-col row), so all 6 edge cndmasks per
//   channel vanish too. +-2 shifts chain off the +-1 results: 6 DPP movs
//   replace 6 bpermutes + 6 cndmasks per channel. -24 DS, -24 VALU per row.
// R9 scar: cvt_pkrtz returns half2 directly -- bit-cast, don't assign to v2f.

typedef _Float16 h2 __attribute__((ext_vector_type(2)));
typedef __fp16 fp16v2 __attribute__((ext_vector_type(2)));

#define WSZ 11
#define RAD 5
#define IMH 256
#define IMW 256
#define BAND 4
#define NBANDS (IMH / BAND)          // 64
#define NPLANES 192                  // 8*8*3
#define NWAVETOT (NPLANES * NBANDS)  // 12288 bands (one wave each)
#define WPB 4                        // waves per block
#define NGRID (NWAVETOT / WPB)       // 3072 blocks of 256 threads
#define NPIXF (192.0f * 256.0f * 256.0f)

// Gaussian(sigma=1.5, ws=11) weights, normalized.
#define GW0 0.001028381f
#define GW1 0.007598770f
#define GW2 0.036000770f
#define GW3 0.109360600f
#define GW4 0.213005700f
#define GW5 0.266011790f

// ---- packed fp16 ops (full-rate VOP3P) ----
__device__ __forceinline__ h2 pk_fma16(h2 a, h2 b, h2 c) {
    h2 d;
    asm("v_pk_fma_f16 %0, %1, %2, %3" : "=v"(d) : "v"(a), "v"(b), "v"(c));
    return d;
}
__device__ __forceinline__ h2 pk_mul16(h2 a, h2 b) {
    h2 d;
    asm("v_pk_mul_f16 %0, %1, %2" : "=v"(d) : "v"(a), "v"(b));
    return d;
}
__device__ __forceinline__ h2 pk_add16(h2 a, h2 b) {
    h2 d;
    asm("v_pk_add_f16 %0, %1, %2" : "=v"(d) : "v"(a), "v"(b));
    return d;
}

union H2U { h2 h; unsigned u; };
__device__ __forceinline__ unsigned h2u(h2 v) { H2U x; x.h = v; return x.u; }
__device__ __forceinline__ h2 u2h(unsigned v) { H2U x; x.u = v; return x.h; }

// DPP whole-wave lane shifts (VALU pipe, no DS). bound_ctrl -> shifted-in
// lanes read 0, which IS the image-edge zero-pad (wave == full row).
// wave_shr:1 = 0x138 (lane n <- lane n-1), wave_shl:1 = 0x130 (lane n <- n+1).
__device__ __forceinline__ h2 dpp_shr1(h2 v) {
    return u2h((unsigned)__builtin_amdgcn_update_dpp(
        0, (int)h2u(v), 0x138, 0xf, 0xf, true));
}
__device__ __forceinline__ h2 dpp_shl1(h2 v) {
    return u2h((unsigned)__builtin_amdgcn_update_dpp(
        0, (int)h2u(v), 0x130, 0xf, 0xf, true));
}

// {lo.h1, hi.h0}
__device__ __forceinline__ h2 albt(h2 hi, h2 lo) {
    return u2h(__builtin_amdgcn_alignbit(h2u(hi), h2u(lo), 16));
}

__device__ __forceinline__ h2 splat16(float s) {
    _Float16 t = (_Float16)s;
    return (h2){t, t};
}
__device__ __forceinline__ h2 zero16() { return (h2){(_Float16)0, (_Float16)0}; }

// clip two floats to [0,1], pack to half2 (v_cvt_pkrtz_f16_f32, 1 instr)
__device__ __forceinline__ h2 clip_pack(float a, float b) {
    a = fminf(fmaxf(a, 0.f), 1.f);
    b = fminf(fmaxf(b, 0.f), 1.f);
    fp16v2 r = __builtin_amdgcn_cvt_pkrtz(a, b);
    return __builtin_bit_cast(h2, r);
}

__global__ __launch_bounds__(256, 4) void ssim_band_kernel(
    const float* __restrict__ pred,
    const float* __restrict__ targ,
    float* __restrict__ partial)
{
    const int tid = threadIdx.x;
    const int lane = tid & 63;
    const int wid = tid >> 6;              // 4 independent waves per block
    const int b = blockIdx.x * WPB + wid;  // global band id, 0..12287
    const int plane = b >> 6;              // 64 bands per plane
    const int band = b & 63;
    const int r0 = band * BAND;

    const float4* __restrict__ pp =
        (const float4*)(pred + (size_t)plane * (IMH * IMW));
    const float4* __restrict__ tp =
        (const float4*)(targ + (size_t)plane * (IMH * IMW));

    const h2 W0 = splat16(GW0), W1 = splat16(GW1), W2 = splat16(GW2),
             W3 = splat16(GW3), W4 = splat16(GW4), W5 = splat16(GW5);
    const h2 wv16[WSZ] = {W0, W1, W2, W3, W4, W5, W4, W3, W2, W1, W0};
    const h2 M2 = splat16(-2.0f);

    // Register ring: rows r-5..r+5 as sum/diff channels s=x+y, d=x-y,
    // 4 cols/lane as 2 half2. Modular-indexed, fully-unrolled -> SSA.
    h2 RS[WSZ][2], RD[WSZ][2];

    // Preload rows r0-5 .. r0+4 into slots 0..9 (zero pad outside image).
#pragma unroll
    for (int j = 0; j < 10; ++j) {
        const int r = r0 - RAD + j;
        float4 a = make_float4(0.f, 0.f, 0.f, 0.f);
        float4 c = a;
        if (r >= 0 && r < IMH) { a = pp[r * 64 + lane]; c = tp[r * 64 + lane]; }
        const h2 x0 = clip_pack(a.x, a.y), x1 = clip_pack(a.z, a.w);
        const h2 y0 = clip_pack(c.x, c.y), y1 = clip_pack(c.z, c.w);
        RS[j][0] = pk_add16(x0, y0);
        RS[j][1] = pk_add16(x1, y1);
        RD[j][0] = pk_fma16(M2, y0, RS[j][0]);   // s - 2y = x - y
        RD[j][1] = pk_fma16(M2, y1, RS[j][1]);
    }

    // Prefetch pipeline: pending holds row r0+RAD+i at iteration i entry.
    float4 pa = make_float4(0.f, 0.f, 0.f, 0.f), pc = pa;
    {
        const int r = r0 + RAD;
        if (r < IMH) { pa = pp[r * 64 + lane]; pc = tp[r * 64 + lane]; }
    }

    const float C1 = 1e-4f, C2 = 9e-4f;
    float lsum = 0.f;

#pragma unroll
    for (int i = 0; i < BAND; ++i) {
        // Consume pending (issued last iteration) into incoming slot.
        const int sIn = (i + 10) % WSZ;
        {
            const h2 x0 = clip_pack(pa.x, pa.y), x1 = clip_pack(pa.z, pa.w);
            const h2 y0 = clip_pack(pc.x, pc.y), y1 = clip_pack(pc.z, pc.w);
            RS[sIn][0] = pk_add16(x0, y0);
            RS[sIn][1] = pk_add16(x1, y1);
            RD[sIn][0] = pk_fma16(M2, y0, RS[sIn][0]);
            RD[sIn][1] = pk_fma16(M2, y1, RS[sIn][1]);
        }

        // Issue next row's loads (wave-uniform guard).
        {
            const int rn = r0 + RAD + i + 1;
            if (rn < IMH) {
                pa = pp[rn * 64 + lane];
                pc = tp[rn * 64 + lane];
            } else {
                pa = make_float4(0.f, 0.f, 0.f, 0.f);
                pc = make_float4(0.f, 0.f, 0.f, 0.f);
            }
        }

        // Vertical pass: 4 channels {s, d, s^2, d^2} x 2 col-pairs.
        h2 vd[4][2];
#pragma unroll
        for (int p = 0; p < 2; ++p) {
            vd[0][p] = zero16(); vd[1][p] = zero16();
            vd[2][p] = zero16(); vd[3][p] = zero16();
        }
#pragma unroll
        for (int k = 0; k < WSZ; ++k) {
            const int sl = (i + k) % WSZ;    // compile-time after unroll
            const h2 wk = wv16[k];
#pragma unroll
            for (int p = 0; p < 2; ++p) {
                const h2 s = RS[sl][p], d = RD[sl][p];
                const h2 ws = pk_mul16(wk, s);
                const h2 wd = pk_mul16(wk, d);
                vd[0][p] = pk_add16(vd[0][p], ws);
                vd[1][p] = pk_add16(vd[1][p], wd);
                vd[2][p] = pk_fma16(ws, s, vd[2][p]);
                vd[3][p] = pk_fma16(wd, d, vd[3][p]);
            }
        }

        // Horizontal pass per channel: 6 DPP wave-shifts (zero-fill edges)
        // + 7 alignbits + 22 pk ops. No DS ops, no edge cndmasks.
        // Window v[0..13] = cols c0-5..c0+8; H0={v5,v6}, H1={v7,v8}.
        h2 hf[4][2];
#pragma unroll
        for (int ch = 0; ch < 4; ++ch) {
            const h2 H0 = vd[ch][0], H1 = vd[ch][1];
            const h2 Gm2 = dpp_shr1(H0);      // {v1, v2}
            const h2 Gm1 = dpp_shr1(H1);      // {v3, v4}
            const h2 Gm3 = dpp_shr1(Gm1);     // {v-1, v0} (lanes 0,1 -> 0)
            const h2 G2  = dpp_shl1(H0);      // {v9, v10}
            const h2 G3  = dpp_shl1(H1);      // {v11, v12}
            const h2 G4  = dpp_shl1(G2);      // {v13, v14} (lanes 62,63 -> 0)
            // Consecutive pairs P_k = {v[k], v[k+1]}.
            const h2 P0  = albt(Gm2, Gm3);
            const h2 P1  = Gm2;
            const h2 P2  = albt(Gm1, Gm2);
            const h2 P3  = Gm1;
            const h2 P4  = albt(H0, Gm1);
            const h2 P5  = H0;
            const h2 P6  = albt(H1, H0);
            const h2 P7  = H1;
            const h2 P8  = albt(G2, H1);
            const h2 P9  = G2;
            const h2 P10 = albt(G3, G2);
            const h2 P11 = G3;
            const h2 P12 = albt(G4, G3);
            // out pair {c0,c1} = sum_k w[k] * P_k
            h2 a0 = pk_mul16(W0, P0);
            a0 = pk_fma16(W1, P1, a0);
            a0 = pk_fma16(W2, P2, a0);
            a0 = pk_fma16(W3, P3, a0);
            a0 = pk_fma16(W4, P4, a0);
            a0 = pk_fma16(W5, P5, a0);
            a0 = pk_fma16(W4, P6, a0);
            a0 = pk_fma16(W3, P7, a0);
            a0 = pk_fma16(W2, P8, a0);
            a0 = pk_fma16(W1, P9, a0);
            a0 = pk_fma16(W0, P10, a0);
            // out pair {c2,c3} = sum_k w[k] * P_{k+2}
            h2 a1 = pk_mul16(W0, P2);
            a1 = pk_fma16(W1, P3, a1);
            a1 = pk_fma16(W2, P4, a1);
            a1 = pk_fma16(W3, P5, a1);
            a1 = pk_fma16(W4, P6, a1);
            a1 = pk_fma16(W5, P7, a1);
            a1 = pk_fma16(W4, P8, a1);
            a1 = pk_fma16(W3, P9, a1);
            a1 = pk_fma16(W2, P10, a1);
            a1 = pk_fma16(W1, P11, a1);
            a1 = pk_fma16(W0, P12, a1);
            hf[ch][0] = a0;
            hf[ch][1] = a1;
        }

        // SSIM epilogue in fp32 from sum/diff moments.
        // ms=G*s, md=G*d, Ss=G*s^2, Sd=G*d^2.
#pragma unroll
        for (int p = 0; p < 2; ++p) {
#pragma unroll
            for (int e = 0; e < 2; ++e) {
                const float ms = (float)hf[0][p][e];
                const float md = (float)hf[1][p][e];
                const float Ss = (float)hf[2][p][e];
                const float Sd = (float)hf[3][p][e];
                const float P = ms * ms, Q = md * md;
                const float mxy2 = 0.5f * (P - Q);          // 2*mx*my
                const float m2s  = 0.5f * (P + Q);          // mx^2+my^2
                const float Ssum = 0.5f * (Ss + Sd);        // Sxx+Syy
                const float ssum = fmaxf(Ssum - m2s, 0.f);  // vx+vy (joint clamp)
                const float sxy2 = fmaf(0.5f, Ss - Sd, -mxy2); // 2*sigma_xy
                const float num = (mxy2 + C1) * (sxy2 + C2);
                const float den = fmaf(m2s + C1, ssum + C2, 1e-8f);
                lsum += num * __builtin_amdgcn_rcpf(den);
            }
        }
        // No ring shift: modular indices rotate statically (unrolled).
    }

    // Wave reduction (64 lanes), then 4-wave LDS combine -> one store/block.
#pragma unroll
    for (int off = 32; off > 0; off >>= 1)
        lsum += __shfl_xor(lsum, off, 64);

    __shared__ float wsum[WPB];
    if (lane == 0) wsum[wid] = lsum;
    __syncthreads();
    if (tid == 0)
        partial[blockIdx.x] = wsum[0] + wsum[1] + wsum[2] + wsum[3];
}

__global__ __launch_bounds__(256) void ssim_finalize(
    const float* __restrict__ partial,
    float* __restrict__ out)
{
    __shared__ float wsum[4];
    const int t = threadIdx.x;  // 256 threads
    float s = 0.f;
    for (int i = t; i < NGRID; i += 256) s += partial[i];
#pragma unroll
    for (int off = 32; off > 0; off >>= 1)
        s += __shfl_xor(s, off, 64);
    const int lane = t & 63, wv = t >> 6;
    if (lane == 0) wsum[wv] = s;
    __syncthreads();
    if (t == 0)
        out[0] = 1.0f - (wsum[0] + wsum[1] + wsum[2] + wsum[3]) / NPIXF;
}

extern "C" void kernel_launch(void* const* d_in, const int* in_sizes, int n_in,
                              void* d_out, int out_size, void* d_ws, size_t ws_size,
                              hipStream_t stream) {
    const float* pred = (const float*)d_in[0];
    const float* targ = (const float*)d_in[1];
    float* out = (float*)d_out;
    float* part = (float*)d_ws;    // 3072 floats = 12 KB scratch

    ssim_band_kernel<<<NGRID, 256, 0, stream>>>(pred, targ, part);
    ssim_finalize<<<1, 256, 0, stream>>>(part, out);
}

// Round 6
// 140.520 us; speedup vs baseline: 1.0937x; 1.0937x over previous
//
#include <hip/hip_runtime.h>

// SSIM loss over [8,8,3,256,256] fp32.
// Wave-per-band structure, packed-FP16 convolutions (v_pk_fma_f16). Epilogue
// (variance differencing + rcp) stays fp32.
// R10: BAND 16->8 + 4 waves/block. Occupancy 26->40, band 78->73us.
// R11/R12: neutral. ERRATA: FETCH/WRITE are KB not MB; HBM always clean.
// R13: full 4x unroll (ring -> SSA, rule-#20 fix) + sum/diff channels
//      (5->4 convs). band 67->60.6us, VGPR 44, VALUBusy ~60%.
// R14 REGRESSION: DPP wave shifts. band 63.7us, VALUBusy 54. v_mov_b32_dpp
//      has wait-state hazards after VALU writes (s_nop padding), and chained
//      DPP serialized; the bpermutes it replaced ran CONCURRENTLY on the DS
//      pipe. Reverted -> bpermute horizontal is the keeper.
// R15: latency attack. Issue floor ~21us vs 60.6 measured, VALUBusy 60% ->
//      40% of cycles idle. Cause: wave-uniform branches around every load
//      (s_cbranch pins loads to their iteration; only 2 loads in flight;
//      vmcnt wait covers ~750cy vs ~900cy HBM cold-miss latency -- FETCH ~=
//      input size, so first touches DO miss to HBM).
//      (a) branchless clamped loads (min/max row + uniform cndmask fixup),
//      (b) 2-deep row prefetch: the load consumed at iter i was issued at
//          iter i-2 (~1500cy cover).
// R9 scar: cvt_pkrtz returns half2 directly -- bit-cast, don't assign to v2f.

typedef _Float16 h2 __attribute__((ext_vector_type(2)));
typedef __fp16 fp16v2 __attribute__((ext_vector_type(2)));

#define WSZ 11
#define RAD 5
#define IMH 256
#define IMW 256
#define BAND 4
#define NBANDS (IMH / BAND)          // 64
#define NPLANES 192                  // 8*8*3
#define NWAVETOT (NPLANES * NBANDS)  // 12288 bands (one wave each)
#define WPB 4                        // waves per block
#define NGRID (NWAVETOT / WPB)       // 3072 blocks of 256 threads
#define NPIXF (192.0f * 256.0f * 256.0f)

// Gaussian(sigma=1.5, ws=11) weights, normalized.
#define GW0 0.001028381f
#define GW1 0.007598770f
#define GW2 0.036000770f
#define GW3 0.109360600f
#define GW4 0.213005700f
#define GW5 0.266011790f

// ---- packed fp16 ops (full-rate VOP3P) ----
__device__ __forceinline__ h2 pk_fma16(h2 a, h2 b, h2 c) {
    h2 d;
    asm("v_pk_fma_f16 %0, %1, %2, %3" : "=v"(d) : "v"(a), "v"(b), "v"(c));
    return d;
}
__device__ __forceinline__ h2 pk_mul16(h2 a, h2 b) {
    h2 d;
    asm("v_pk_mul_f16 %0, %1, %2" : "=v"(d) : "v"(a), "v"(b));
    return d;
}
__device__ __forceinline__ h2 pk_add16(h2 a, h2 b) {
    h2 d;
    asm("v_pk_add_f16 %0, %1, %2" : "=v"(d) : "v"(a), "v"(b));
    return d;
}

union H2U { h2 h; unsigned u; };
__device__ __forceinline__ unsigned h2u(h2 v) { H2U x; x.h = v; return x.u; }
__device__ __forceinline__ h2 u2h(unsigned v) { H2U x; x.u = v; return x.h; }

// raw lane gather: src lane index precomputed (byte addr = lane*4)
__device__ __forceinline__ h2 bperm(int idx, h2 v) {
    return u2h((unsigned)__builtin_amdgcn_ds_bpermute(idx, (int)h2u(v)));
}
// {lo.h1, hi.h0}
__device__ __forceinline__ h2 albt(h2 hi, h2 lo) {
    return u2h(__builtin_amdgcn_alignbit(h2u(hi), h2u(lo), 16));
}

__device__ __forceinline__ h2 splat16(float s) {
    _Float16 t = (_Float16)s;
    return (h2){t, t};
}
__device__ __forceinline__ h2 zero16() { return (h2){(_Float16)0, (_Float16)0}; }

// clip two floats to [0,1], pack to half2 (v_cvt_pkrtz_f16_f32, 1 instr)
__device__ __forceinline__ h2 clip_pack(float a, float b) {
    a = fminf(fmaxf(a, 0.f), 1.f);
    b = fminf(fmaxf(b, 0.f), 1.f);
    fp16v2 r = __builtin_amdgcn_cvt_pkrtz(a, b);
    return __builtin_bit_cast(h2, r);
}

__global__ __launch_bounds__(256, 4) void ssim_band_kernel(
    const float* __restrict__ pred,
    const float* __restrict__ targ,
    float* __restrict__ partial)
{
    const int tid = threadIdx.x;
    const int lane = tid & 63;
    const int wid = tid >> 6;              // 4 independent waves per block
    const int b = blockIdx.x * WPB + wid;  // global band id, 0..12287
    const int plane = b >> 6;              // 64 bands per plane
    const int band = b & 63;
    const int r0 = band * BAND;

    const float4* __restrict__ pp =
        (const float4*)(pred + (size_t)plane * (IMH * IMW));
    const float4* __restrict__ tp =
        (const float4*)(targ + (size_t)plane * (IMH * IMW));

    const h2 W0 = splat16(GW0), W1 = splat16(GW1), W2 = splat16(GW2),
             W3 = splat16(GW3), W4 = splat16(GW4), W5 = splat16(GW5);
    const h2 wv16[WSZ] = {W0, W1, W2, W3, W4, W5, W4, W3, W2, W1, W0};
    const h2 M2 = splat16(-2.0f);

    // Hoisted shuffle machinery: 4 index vectors + 4 edge predicates.
    const int iu1 = (lane - 1) << 2;
    const int iu2 = (lane - 2) << 2;
    const int id1 = (lane + 1) << 2;
    const int id2 = (lane + 2) << 2;
    const bool mu1 = lane >= 1;
    const bool mu2 = lane >= 2;
    const bool md1 = lane <= 62;
    const bool md2 = lane <= 61;

    // Register ring: rows r-5..r+5 as sum/diff channels s=x+y, d=x-y,
    // 4 cols/lane as 2 half2. Modular-indexed, fully-unrolled -> SSA.
    h2 RS[WSZ][2], RD[WSZ][2];

    // Preload rows r0-5 .. r0+4 into slots 0..9. Branchless: clamped row
    // address (always in-bounds load), OOB rows zeroed via uniform cndmask.
#pragma unroll
    for (int j = 0; j < 10; ++j) {
        const int r = r0 - RAD + j;
        const int rc = min(max(r, 0), IMH - 1);
        const bool oob = (r < 0) | (r >= IMH);
        const float4 a = pp[rc * 64 + lane];
        const float4 c = tp[rc * 64 + lane];
        const h2 x0 = clip_pack(a.x, a.y), x1 = clip_pack(a.z, a.w);
        const h2 y0 = clip_pack(c.x, c.y), y1 = clip_pack(c.z, c.w);
        h2 s0 = pk_add16(x0, y0);
        h2 s1 = pk_add16(x1, y1);
        h2 d0 = pk_fma16(M2, y0, s0);   // s - 2y = x - y
        h2 d1 = pk_fma16(M2, y1, s1);
        RS[j][0] = oob ? zero16() : s0;
        RS[j][1] = oob ? zero16() : s1;
        RD[j][0] = oob ? zero16() : d0;
        RD[j][1] = oob ? zero16() : d1;
    }

    // 2-deep prefetch pipeline: P[i&1] holds row r0+RAD+i at iter i entry.
    float4 PA[2], PC[2];
    {
        const int ra = min(r0 + RAD, IMH - 1);       // row for iter 0
        const int rb = min(r0 + RAD + 1, IMH - 1);   // row for iter 1
        PA[0] = pp[ra * 64 + lane]; PC[0] = tp[ra * 64 + lane];
        PA[1] = pp[rb * 64 + lane]; PC[1] = tp[rb * 64 + lane];
    }

    const float C1 = 1e-4f, C2 = 9e-4f;
    float lsum = 0.f;

#pragma unroll
    for (int i = 0; i < BAND; ++i) {
        // Stage pending row r0+RAD+i (loaded 2 iters ago) into slot sIn.
        const int sIn = (i + 10) % WSZ;
        {
            const float4 a = PA[i & 1], c = PC[i & 1];
            const bool oob = (r0 + RAD + i) >= IMH;  // uniform
            const h2 x0 = clip_pack(a.x, a.y), x1 = clip_pack(a.z, a.w);
            const h2 y0 = clip_pack(c.x, c.y), y1 = clip_pack(c.z, c.w);
            h2 s0 = pk_add16(x0, y0);
            h2 s1 = pk_add16(x1, y1);
            h2 d0 = pk_fma16(M2, y0, s0);
            h2 d1 = pk_fma16(M2, y1, s1);
            RS[sIn][0] = oob ? zero16() : s0;
            RS[sIn][1] = oob ? zero16() : s1;
            RD[sIn][0] = oob ? zero16() : d0;
            RD[sIn][1] = oob ? zero16() : d1;
        }

        // Issue loads for row r0+RAD+i+2 into the slot just consumed.
        // Branchless: clamped address, harmless duplicate read at the edge.
        {
            const int rn = min(r0 + RAD + i + 2, IMH - 1);
            PA[i & 1] = pp[rn * 64 + lane];
            PC[i & 1] = tp[rn * 64 + lane];
        }

        // Vertical pass: 4 channels {s, d, s^2, d^2} x 2 col-pairs.
        h2 vd[4][2];
#pragma unroll
        for (int p = 0; p < 2; ++p) {
            vd[0][p] = zero16(); vd[1][p] = zero16();
            vd[2][p] = zero16(); vd[3][p] = zero16();
        }
#pragma unroll
        for (int k = 0; k < WSZ; ++k) {
            const int sl = (i + k) % WSZ;    // compile-time after unroll
            const h2 wk = wv16[k];
#pragma unroll
            for (int p = 0; p < 2; ++p) {
                const h2 s = RS[sl][p], d = RD[sl][p];
                const h2 ws = pk_mul16(wk, s);
                const h2 wd = pk_mul16(wk, d);
                vd[0][p] = pk_add16(vd[0][p], ws);
                vd[1][p] = pk_add16(vd[1][p], wd);
                vd[2][p] = pk_fma16(ws, s, vd[2][p]);
                vd[3][p] = pk_fma16(wd, d, vd[3][p]);
            }
        }

        // Horizontal pass per channel (R13 keeper): 6 bpermutes (DS pipe,
        // overlaps VALU) + 6 cndmask edge guards + 7 alignbits + 22 pk ops.
        h2 hf[4][2];
#pragma unroll
        for (int ch = 0; ch < 4; ++ch) {
            const h2 H0 = vd[ch][0], H1 = vd[ch][1];
            h2 Gm3 = bperm(iu2, H1);      // {v-1, v0}
            h2 Gm2 = bperm(iu1, H0);      // {v1, v2}
            h2 Gm1 = bperm(iu1, H1);      // {v3, v4}
            h2 G2  = bperm(id1, H0);      // {v9, v10}
            h2 G3  = bperm(id1, H1);      // {v11, v12}
            h2 G4  = bperm(id2, H0);      // {v13, v14}
            Gm3 = mu2 ? Gm3 : zero16();
            Gm2 = mu1 ? Gm2 : zero16();
            Gm1 = mu1 ? Gm1 : zero16();
            G2  = md1 ? G2  : zero16();
            G3  = md1 ? G3  : zero16();
            G4  = md2 ? G4  : zero16();
            // Consecutive pairs P_k = {v[k], v[k+1]}.
            const h2 P0  = albt(Gm2, Gm3);
            const h2 P1  = Gm2;
            const h2 P2  = albt(Gm1, Gm2);
            const h2 P3  = Gm1;
            const h2 P4  = albt(H0, Gm1);
            const h2 P5  = H0;
            const h2 P6  = albt(H1, H0);
            const h2 P7  = H1;
            const h2 P8  = albt(G2, H1);
            const h2 P9  = G2;
            const h2 P10 = albt(G3, G2);
            const h2 P11 = G3;
            const h2 P12 = albt(G4, G3);
            // out pair {c0,c1} = sum_k w[k] * P_k
            h2 a0 = pk_mul16(W0, P0);
            a0 = pk_fma16(W1, P1, a0);
            a0 = pk_fma16(W2, P2, a0);
            a0 = pk_fma16(W3, P3, a0);
            a0 = pk_fma16(W4, P4, a0);
            a0 = pk_fma16(W5, P5, a0);
            a0 = pk_fma16(W4, P6, a0);
            a0 = pk_fma16(W3, P7, a0);
            a0 = pk_fma16(W2, P8, a0);
            a0 = pk_fma16(W1, P9, a0);
            a0 = pk_fma16(W0, P10, a0);
            // out pair {c2,c3} = sum_k w[k] * P_{k+2}
            h2 a1 = pk_mul16(W0, P2);
            a1 = pk_fma16(W1, P3, a1);
            a1 = pk_fma16(W2, P4, a1);
            a1 = pk_fma16(W3, P5, a1);
            a1 = pk_fma16(W4, P6, a1);
            a1 = pk_fma16(W5, P7, a1);
            a1 = pk_fma16(W4, P8, a1);
            a1 = pk_fma16(W3, P9, a1);
            a1 = pk_fma16(W2, P10, a1);
            a1 = pk_fma16(W1, P11, a1);
            a1 = pk_fma16(W0, P12, a1);
            hf[ch][0] = a0;
            hf[ch][1] = a1;
        }

        // SSIM epilogue in fp32 from sum/diff moments.
        // ms=G*s, md=G*d, Ss=G*s^2, Sd=G*d^2.
#pragma unroll
        for (int p = 0; p < 2; ++p) {
#pragma unroll
            for (int e = 0; e < 2; ++e) {
                const float ms = (float)hf[0][p][e];
                const float md = (float)hf[1][p][e];
                const float Ss = (float)hf[2][p][e];
                const float Sd = (float)hf[3][p][e];
                const float P = ms * ms, Q = md * md;
                const float mxy2 = 0.5f * (P - Q);          // 2*mx*my
                const float m2s  = 0.5f * (P + Q);          // mx^2+my^2
                const float Ssum = 0.5f * (Ss + Sd);        // Sxx+Syy
                const float ssum = fmaxf(Ssum - m2s, 0.f);  // vx+vy (joint clamp)
                const float sxy2 = fmaf(0.5f, Ss - Sd, -mxy2); // 2*sigma_xy
                const float num = (mxy2 + C1) * (sxy2 + C2);
                const float den = fmaf(m2s + C1, ssum + C2, 1e-8f);
                lsum += num * __builtin_amdgcn_rcpf(den);
            }
        }
        // No ring shift: modular indices rotate statically (unrolled).
    }

    // Wave reduction (64 lanes), then 4-wave LDS combine -> one store/block.
#pragma unroll
    for (int off = 32; off > 0; off >>= 1)
        lsum += __shfl_xor(lsum, off, 64);

    __shared__ float wsum[WPB];
    if (lane == 0) wsum[wid] = lsum;
    __syncthreads();
    if (tid == 0)
        partial[blockIdx.x] = wsum[0] + wsum[1] + wsum[2] + wsum[3];
}

__global__ __launch_bounds__(256) void ssim_finalize(
    const float* __restrict__ partial,
    float* __restrict__ out)
{
    __shared__ float wsum[4];
    const int t = threadIdx.x;  // 256 threads
    float s = 0.f;
    for (int i = t; i < NGRID; i += 256) s += partial[i];
#pragma unroll
    for (int off = 32; off > 0; off >>= 1)
        s += __shfl_xor(s, off, 64);
    const int lane = t & 63, wv = t >> 6;
    if (lane == 0) wsum[wv] = s;
    __syncthreads();
    if (t == 0)
        out[0] = 1.0f - (wsum[0] + wsum[1] + wsum[2] + wsum[3]) / NPIXF;
}

extern "C" void kernel_launch(void* const* d_in, const int* in_sizes, int n_in,
                              void* d_out, int out_size, void* d_ws, size_t ws_size,
                              hipStream_t stream) {
    const float* pred = (const float*)d_in[0];
    const float* targ = (const float*)d_in[1];
    float* out = (float*)d_out;
    float* part = (float*)d_ws;    // 3072 floats = 12 KB scratch

    ssim_band_kernel<<<NGRID, 256, 0, stream>>>(pred, targ, part);
    ssim_finalize<<<1, 256, 0, stream>>>(part, out);
}